// Round 1
// 142.896 us; speedup vs baseline: 1.0146x; 1.0146x over previous
//
#include <hip/hip_runtime.h>
#include <hip/hip_bf16.h>

#define N_NODES 10000
#define N_EDGES 640000
#define CH 128
#define KN 118   // node_feat inner dim

typedef _Float16 h8 __attribute__((ext_vector_type(8)));
typedef float f32x4 __attribute__((ext_vector_type(4)));
typedef float v2f __attribute__((ext_vector_type(2)));

// K1: fold weights, TRANSPOSED + padded for the MFMA k2:
//   Mt[cg][k] = f16( sum_j Wn[k][j] * Wa1[mat*128 + j][c] ),  cg = mat*128+c,
//   k in [0,118); Mt[cg][118..127] = 0.
//   V[cg] = bn . Wa1col  (+ ba1[c] for mat==1), f32.
// Extra block (mat==2): w495[c] = 0.495*w2[c] (f32, k3's |t|-term weights),
// and zero-pad Mt's k=118..127 columns.
__global__ __launch_bounds__(128) void k1_weights(
    const float* __restrict__ Wn, const float* __restrict__ bn,
    const float* __restrict__ Wa1, const float* __restrict__ ba1,
    const float* __restrict__ w2, _Float16* __restrict__ Mt,
    float* __restrict__ V, float* __restrict__ w495) {
  int c = threadIdx.x;                 // 0..127
  int mat = blockIdx.x / 119;          // 0: src-half, 1: dst-half, 2: misc
  int i = blockIdx.x % 119;            // 0..117 weight rows, 118 = bias row
  if (mat == 2) {
    w495[c] = 0.495f * w2[c];
#pragma unroll
    for (int cg = c; cg < 256; cg += 128)
#pragma unroll
      for (int p = 118; p < 128; ++p) Mt[cg * 128 + p] = (_Float16)0.f;
    return;
  }
  const float* B = Wa1 + mat * CH * CH;
  const float* a = (i < KN) ? (Wn + i * CH) : bn;
  float acc = 0.f;
#pragma unroll 8
  for (int j = 0; j < CH; ++j) acc = fmaf(a[j], B[j * CH + c], acc);
  int cg = mat * CH + c;
  if (i < KN) {
    Mt[cg * 128 + i] = (_Float16)acc;  // transposed: [col][k]
  } else {
    if (mat == 1) acc += ba1[c];
    V[cg] = acc;
  }
}

// K2 (MFMA): hidden = nf[n][:] . M[:][cg] + V[cg]  (f32)
// Epilogue now does the lrelu linear/nonlinear split:
//   T8[mat][n][c] = fp8_e4m3(hidden)            (|t| term, quantized)
//   P[n] = 0.505 * sum_c w2[c]*S[n][c]  (f32, EXACT — no quantization)
//   Q[n] = 0.505 * sum_c w2[c]*D[n][c]  (f32, EXACT)
// 128 threads = 2 waves; 32 nodes per block; each wave: 16 nodes x 256 cols
// via 16 col-tiles x 4 K-steps of mfma_f32_16x16x32_f16. Mt (64 KB f16)
// staged in LDS with an XOR-8 k-swizzle (kills the stride-256B bank clash).
// Fragment layouts (verified): A[m=lane&15][k=quad*8+j], B[n=lane&15][k=...],
// C/D: col=lane&15, row=quad*4+reg.
__global__ __launch_bounds__(128) void k2_mfma(
    const float* __restrict__ nf, const _Float16* __restrict__ Mt,
    const float* __restrict__ V, const float* __restrict__ w2,
    unsigned char* __restrict__ T8, float* __restrict__ P,
    float* __restrict__ Q) {
  __shared__ _Float16 Blds[256 * 128];   // 64 KB
  int tx = threadIdx.x;

  // Stage Mt -> LDS in 16B chunks, applying the k-swizzle:
  // element (cg,k) lives at Blds[cg*128 + (k ^ ((cg&7)*8))].
#pragma unroll
  for (int it = 0; it < 32; ++it) {
    int chunk = it * 128 + tx;          // 0..4095 chunks of 8 f16
    int cg = chunk >> 4;
    int k0 = (chunk & 15) << 3;
    h8 v = *(const h8*)(Mt + cg * 128 + k0);
    *(h8*)(Blds + cg * 128 + (k0 ^ ((cg & 7) << 3))) = v;
  }

  int wave = tx >> 6;
  int lane = tx & 63;
  int m = lane & 15;                    // node within wave tile / col within ct
  int quad = lane >> 4;
  int nbase = blockIdx.x * 32 + wave * 16;
  int node = nbase + m;
  const float* arow = nf + (size_t)(node < N_NODES ? node : 0) * KN;

  h8 afrag[4];
#pragma unroll
  for (int s = 0; s < 4; ++s) {
#pragma unroll
    for (int j = 0; j < 8; ++j) {
      int k = s * 32 + quad * 8 + j;
      afrag[s][j] = (k < KN) ? (_Float16)arow[k] : (_Float16)0.f;
    }
  }
  __syncthreads();

  f32x4 acc[16];
#pragma unroll
  for (int ct = 0; ct < 16; ++ct) acc[ct] = f32x4{0.f, 0.f, 0.f, 0.f};
  int swz = (m & 7) << 3;               // cg&7 == n&7 within a col-tile
#pragma unroll
  for (int ct = 0; ct < 16; ++ct) {
    const _Float16* brow = Blds + (ct * 16 + m) * 128;
#pragma unroll
    for (int s = 0; s < 4; ++s) {
      h8 b = *(const h8*)(brow + ((s * 32 + quad * 8) ^ swz));
      acc[ct] = __builtin_amdgcn_mfma_f32_16x16x32_f16(afrag[s], b, acc[ct], 0, 0, 0);
    }
  }

  // Epilogue: bias in f32; accumulate exact P/Q; store fp8.
  float psum[4] = {0.f, 0.f, 0.f, 0.f};
  float qsum[4] = {0.f, 0.f, 0.f, 0.f};
  int nd0 = nbase + quad * 4;
#pragma unroll
  for (int ct = 0; ct < 16; ++ct) {
    int cg = ct * 16 + m;
    float bias = V[cg];
    float w505 = 0.505f * w2[cg & (CH - 1)];
    int mat = cg >> 7;
    unsigned char* tp = T8 + ((size_t)mat * N_NODES + nd0) * CH + (cg & (CH - 1));
#pragma unroll
    for (int r = 0; r < 4; ++r) {
      float v = acc[ct][r] + bias;
      if (mat == 0) psum[r] += w505 * v; else qsum[r] += w505 * v;
      unsigned q8 = (unsigned)__builtin_amdgcn_cvt_pk_fp8_f32(v, 0.f, 0, false) & 0xffu;
      if (nd0 + r < N_NODES) tp[(size_t)r * CH] = (unsigned char)q8;
    }
  }
  // Reduce P/Q partial sums across the 16 m-lanes (xor 1,2,4,8 stays in-group).
#pragma unroll
  for (int r = 0; r < 4; ++r) {
    float ps = psum[r], qs = qsum[r];
#pragma unroll
    for (int t = 1; t < 16; t <<= 1) {
      ps += __shfl_xor(ps, t);
      qs += __shfl_xor(qs, t);
    }
    if (m == r && nd0 + r < N_NODES) {
      P[nd0 + r] = ps;
      Q[nd0 + r] = qs;
    }
  }
}

// 0.495*w . |s+d| over 8 channels, fp8 inputs decoded in-register.
__device__ __forceinline__ float edge_abs8(uint2 sbv, uint2 dbv,
                                           f32x4 wa, f32x4 wb) {
  v2f s0 = __builtin_amdgcn_cvt_pk_f32_fp8(sbv.x, false);
  v2f s1 = __builtin_amdgcn_cvt_pk_f32_fp8(sbv.x, true);
  v2f s2 = __builtin_amdgcn_cvt_pk_f32_fp8(sbv.y, false);
  v2f s3 = __builtin_amdgcn_cvt_pk_f32_fp8(sbv.y, true);
  v2f d0 = __builtin_amdgcn_cvt_pk_f32_fp8(dbv.x, false);
  v2f d1 = __builtin_amdgcn_cvt_pk_f32_fp8(dbv.x, true);
  v2f d2 = __builtin_amdgcn_cvt_pk_f32_fp8(dbv.y, false);
  v2f d3 = __builtin_amdgcn_cvt_pk_f32_fp8(dbv.y, true);
  float acc;
  acc = __builtin_fabsf(s0.x + d0.x) * wa.x;
  acc = fmaf(__builtin_fabsf(s0.y + d0.y), wa.y, acc);
  acc = fmaf(__builtin_fabsf(s1.x + d1.x), wa.z, acc);
  acc = fmaf(__builtin_fabsf(s1.y + d1.y), wa.w, acc);
  acc = fmaf(__builtin_fabsf(s2.x + d2.x), wb.x, acc);
  acc = fmaf(__builtin_fabsf(s2.y + d2.y), wb.y, acc);
  acc = fmaf(__builtin_fabsf(s3.x + d3.x), wb.z, acc);
  acc = fmaf(__builtin_fabsf(s3.y + d3.y), wb.w, acc);
  return acc;
}

// K3: out[e] = b2 + P[src[e]] + Q[dst[e]] + sum_c 0.495*w2[c]*|S[src]+D[dst]|
// 16 lanes per edge-QUAD slot, 8 channels per lane, 4 edges per thread.
// fp8 tables: 2.56 MB total -> fits per-XCD L2; 64 B gather payload/thread
// (was 128 B) -> __launch_bounds__(256,8) pins full 8 waves/SIMD for MLP.
__global__ __launch_bounds__(256, 8) void k3_edges(
    const int* __restrict__ src, const int* __restrict__ dst,
    const unsigned char* __restrict__ S8, const unsigned char* __restrict__ D8,
    const float* __restrict__ w495, const float* __restrict__ P,
    const float* __restrict__ Q, const float* __restrict__ b2,
    float* __restrict__ out) {
  int tid = blockIdx.x * 256 + threadIdx.x;
  int g = tid >> 4;             // edge-quad id, 0..N_EDGES/4-1
  int sub = tid & 15;
  int c0 = sub << 3;            // 8 channels per lane

  f32x4 wa = *(const f32x4*)(w495 + c0);
  f32x4 wb = *(const f32x4*)(w495 + c0 + 4);
  int4 s4 = *(const int4*)(src + 4 * g);   // broadcast across the 16 lanes
  int4 d4 = *(const int4*)(dst + 4 * g);

  const unsigned char* Sp = S8 + c0;
  const unsigned char* Dp = D8 + c0;
  uint2 sb0 = *(const uint2*)(Sp + ((unsigned)s4.x << 7));
  uint2 db0 = *(const uint2*)(Dp + ((unsigned)d4.x << 7));
  uint2 sb1 = *(const uint2*)(Sp + ((unsigned)s4.y << 7));
  uint2 db1 = *(const uint2*)(Dp + ((unsigned)d4.y << 7));
  uint2 sb2 = *(const uint2*)(Sp + ((unsigned)s4.z << 7));
  uint2 db2 = *(const uint2*)(Dp + ((unsigned)d4.z << 7));
  uint2 sb3 = *(const uint2*)(Sp + ((unsigned)s4.w << 7));
  uint2 db3 = *(const uint2*)(Dp + ((unsigned)d4.w << 7));

  float a0 = edge_abs8(sb0, db0, wa, wb);
  float a1 = edge_abs8(sb1, db1, wa, wb);
  float a2 = edge_abs8(sb2, db2, wa, wb);
  float a3 = edge_abs8(sb3, db3, wa, wb);

  // packed butterfly: after this, lane (sub&3)==k holds sum of edge k
  float r0 = a0 + __shfl_xor(a0, 1);
  float r1 = a1 + __shfl_xor(a1, 1);
  float r2 = a2 + __shfl_xor(a2, 1);
  float r3 = a3 + __shfl_xor(a3, 1);
  float v1 = (sub & 1) ? r1 : r0;
  float v2 = (sub & 1) ? r3 : r2;
  float t1 = v1 + __shfl_xor(v1, 2);
  float t2 = v2 + __shfl_xor(v2, 2);
  float u = (sub & 2) ? t2 : t1;
  u += __shfl_xor(u, 4);
  u += __shfl_xor(u, 8);

  if (sub < 4) {
    int si = sub == 0 ? s4.x : sub == 1 ? s4.y : sub == 2 ? s4.z : s4.w;
    int di = sub == 0 ? d4.x : sub == 1 ? d4.y : sub == 2 ? d4.z : d4.w;
    out[4 * g + sub] = u + P[si] + Q[di] + b2[0];
  }
}

extern "C" void kernel_launch(void* const* d_in, const int* in_sizes, int n_in,
                              void* d_out, int out_size, void* d_ws, size_t ws_size,
                              hipStream_t stream) {
  const float* nf  = (const float*)d_in[0];
  // d_in[1] edge_feat, d_in[6] W_edge, d_in[7] b_edge: unused by the output
  const int*   src = (const int*)d_in[2];
  const int*   dst = (const int*)d_in[3];
  const float* Wn  = (const float*)d_in[4];
  const float* bn  = (const float*)d_in[5];
  const float* Wa1 = (const float*)d_in[8];
  const float* ba1 = (const float*)d_in[9];
  const float* Wa2 = (const float*)d_in[10];
  const float* ba2 = (const float*)d_in[11];
  float* out = (float*)d_out;

  char* ws = (char*)d_ws;
  _Float16* Mt   = (_Float16*)ws;               // [256][128] f16 = 64 KB
  float*    V    = (float*)(ws + 65536);        // [256] f32
  float*    w495 = (float*)(ws + 66560);        // [128] f32
  float*    P    = (float*)(ws + 67072);        // [10000] f32
  float*    Q    = (float*)(ws + 107072);       // [10000] f32
  unsigned char* T8 = (unsigned char*)(ws + 147072);  // [2][10000][128] fp8
  unsigned char* S8 = T8;
  unsigned char* D8 = T8 + (size_t)N_NODES * CH;

  k1_weights<<<239, 128, 0, stream>>>(Wn, bn, Wa1, ba1, Wa2, Mt, V, w495);
  k2_mfma<<<(N_NODES + 31) / 32, 128, 0, stream>>>(nf, Mt, V, Wa2, T8, P, Q);
  k3_edges<<<(N_EDGES / 4 * 16) / 256, 256, 0, stream>>>(src, dst, S8, D8, w495, P, Q, ba2, out);
}